// Round 9
// baseline (473.026 us; speedup 1.0000x reference)
//
#include <hip/hip_runtime.h>
#include <hip/hip_bf16.h>
#include <math.h>

#define B_ 2
#define T_ 2048
#define C_ 1024
#define H_ 16
#define D_ 64
#define F_ 4096
#define BT_ (B_*T_)

typedef __attribute__((ext_vector_type(8))) short bf16x8;
typedef __attribute__((ext_vector_type(4))) float f32x4;

__device__ __forceinline__ float bfraw2f(unsigned int u){
    union { unsigned int i; float f; } c; c.i = u << 16; return c.f;
}
// f32 -> bf16 raw bits, round-to-nearest-even
__device__ __forceinline__ short f2bfraw(float f){
    union { float f; unsigned int i; } c; c.f = f;
    unsigned int u = c.i;
    u += 0x7fffu + ((u >> 16) & 1u);
    return (short)(u >> 16);
}
// async global->LDS, 16B per lane; LDS dest = wave-uniform base + lane*16
__device__ __forceinline__ void gl2lds16(const void* g, void* l) {
    __builtin_amdgcn_global_load_lds(
        (const __attribute__((address_space(1))) unsigned int*)g,
        (__attribute__((address_space(3))) unsigned int*)l,
        16, 0, 0);
}

// ------- merged weight convert + transpose, 1D flattened grid --------------
// 3072 blocks total: [0,768) qkv, [768,1024) out, [1024,2048) ff1, [2048,3072) ff2.
__global__ __launch_bounds__(256) void wconv_all(const float* qkv_w, short* qkvwT,
                                                 const float* out_w, short* outwT,
                                                 const float* ff1_w, short* ff1wT,
                                                 const float* ff2_w, short* ff2wT)
{
    int id = blockIdx.x;
    const float* W; short* Wt; int K, N;
    if (id < 768)       { W = qkv_w; Wt = qkvwT; K = C_; N = 3 * C_; }
    else if (id < 1024) { id -= 768;  W = out_w; Wt = outwT; K = C_; N = C_; }
    else if (id < 2048) { id -= 1024; W = ff1_w; Wt = ff1wT; K = C_; N = F_; }
    else                { id -= 2048; W = ff2_w; Wt = ff2wT; K = F_; N = C_; }
    int ntile = N >> 6;
    int n0 = (id % ntile) * 64, k0 = (id / ntile) * 64;

    __shared__ short tile[64][65];
    int t = threadIdx.x;
#pragma unroll
    for (int i = 0; i < 4; i++) {
        int idx = t + i * 256;
        int r = idx >> 4, c4 = (idx & 15) * 4;
        float4 u = *(const float4*)(W + (size_t)(k0 + r) * N + n0 + c4);
        tile[c4 + 0][r] = f2bfraw(u.x);
        tile[c4 + 1][r] = f2bfraw(u.y);
        tile[c4 + 2][r] = f2bfraw(u.z);
        tile[c4 + 3][r] = f2bfraw(u.w);
    }
    __syncthreads();
#pragma unroll
    for (int i = 0; i < 2; i++) {
        int idx = t + i * 256;
        int r = idx >> 3, c8 = (idx & 7) * 8;
        short v[8];
#pragma unroll
        for (int u8 = 0; u8 < 8; u8++) v[u8] = tile[r][c8 + u8];
        *(uint4*)(Wt + (size_t)(n0 + r) * K + k0 + c8) = *(const uint4*)v;
    }
}

// ---------------- V transpose: qkv V-slots -> Vt[b*H+h][d][t] (bf16) ----------
__global__ __launch_bounds__(256) void v_transpose(const __hip_bfloat16* __restrict__ qkv,
                                                   short* __restrict__ vt)
{
    __shared__ short tile[64][65];   // [d][token]
    int kb = blockIdx.x * 64;        // token tile base
    int h = blockIdx.y, b = blockIdx.z;
    const short* src = (const short*)qkv + (size_t)b * T_ * 3 * C_ + 2 * C_ + h * D_;
    int t = threadIdx.x;
#pragma unroll
    for (int i = 0; i < 2; i++) {
        int idx = t + i * 256;
        int r = idx >> 3, c8 = (idx & 7) * 8;   // r: token-rel, c8: d
        bf16x8 v = *(const bf16x8*)(src + (size_t)(kb + r) * 3 * C_ + c8);
#pragma unroll
        for (int u = 0; u < 8; u++) tile[c8 + u][r] = v[u];
    }
    __syncthreads();
    short* dst = vt + (size_t)(b * H_ + h) * D_ * T_ + kb;
#pragma unroll
    for (int i = 0; i < 2; i++) {
        int idx = t + i * 256;
        int r = idx >> 3, c8 = (idx & 7) * 8;   // r: d, c8: token-rel
        short v[8];
#pragma unroll
        for (int u = 0; u < 8; u++) v[u] = tile[r][c8 + u];
        *(uint4*)(dst + (size_t)r * T_ + c8) = *(const uint4*)v;
    }
}

// ---------------- fused LayerNorm (fp32 in, bf16 out) ----------------
__global__ __launch_bounds__(256) void ln_fused(const float* __restrict__ x, int ldx,
                                                const float* __restrict__ g,
                                                const float* __restrict__ b,
                                                __hip_bfloat16* out, int ldo)
{
    __shared__ float sm1[4], sm2[4];
    __shared__ float smu, srs;
    int row = blockIdx.x, t = threadIdx.x;
    const float* xr = x + (size_t)row * ldx;
    float v[4]; float s = 0.f, ss = 0.f;
#pragma unroll
    for (int i = 0; i < 4; i++) {
        float f = xr[t + i * 256];
        v[i] = f; s += f; ss += f * f;
    }
#pragma unroll
    for (int off = 32; off >= 1; off >>= 1) {
        s  += __shfl_xor(s,  off);
        ss += __shfl_xor(ss, off);
    }
    int wave = t >> 6, lane = t & 63;
    if (!lane) { sm1[wave] = s; sm2[wave] = ss; }
    __syncthreads();
    if (t == 0) {
        s  = sm1[0] + sm1[1] + sm1[2] + sm1[3];
        ss = sm2[0] + sm2[1] + sm2[2] + sm2[3];
        float mu  = s * (1.f / C_);
        float var = ss * (1.f / C_) - mu * mu;
        if (var < 0.f) var = 0.f;
        smu = mu; srs = rsqrtf(var + 1e-5f);
    }
    __syncthreads();
    float mu = smu, rs = srs;
#pragma unroll
    for (int i = 0; i < 4; i++) {
        int c = t + i * 256;
        out[(size_t)row * ldo + c] = __float2bfloat16((v[i] - mu) * rs * g[c] + b[c]);
    }
}

// ---------- gemm8p: 256Mx128N, BK=64, 8 waves, 3-buf counted-vmcnt ----------
// out = A[M,K](bf16) @ Wt[N,K]^T + bias; ACT: 0=bf16, 1=bf16+GELU,
// 2=fp32 + fp32 residual (res may alias out). koff applies to Wt only.
// Wave-tile 64x64 (proven fragment math). LDS rows = 64 bf16 (128 B), XOR-
// swizzled via pre-swizzled global source: slot c of row r holds global
// chunk c^(r&7); read slot = q^(r&7). 3 LDS buffers (144 KB): at iter t stage
// tile t+2; s_waitcnt vmcnt(6) at tile end waits only tile t+1's 6 loads.
template<int ACT>
__global__ __launch_bounds__(512, 2) void gemm8p(
    const __hip_bfloat16* A, int lda,
    const short* Wt, int ldw, int noff, int koff,
    const float* __restrict__ bias, int boff,
    const float* res, int ldres,
    void* out, int ldo,
    int K)
{
    __shared__ __align__(16) short As[3][256 * 64];   // [buf][m][k], swizzled
    __shared__ __align__(16) short Bs[3][128 * 64];   // [buf][n][k], swizzled
    int tid = threadIdx.x;
    int w = tid >> 6, lane = tid & 63;
    int quad = lane >> 4, l16 = lane & 15;
    int wm = w >> 2, wn = w & 3;                      // placeholder (fixed below)
    wm = w >> 1; wn = w & 1;                          // 4M x 2N wave grid
    int m0 = blockIdx.y * 256, n0 = blockIdx.x * 128;

    // staging geometry: lane8 = row-within-8, cswz = pre-swizzled chunk (elems)
    int lane8 = lane >> 3;
    int cswz  = ((lane & 7) ^ lane8) * 8;
    const __hip_bfloat16* AgS = A + (size_t)(m0 + w * 32 + lane8) * lda + cswz;
    const short*          BgS = Wt + (size_t)(noff + n0 + w * 16 + lane8) * ldw + koff + cswz;

    f32x4 acc[4][4];
#pragma unroll
    for (int i = 0; i < 4; i++)
#pragma unroll
        for (int j = 0; j < 4; j++) acc[i][j] = (f32x4){0.f, 0.f, 0.f, 0.f};

    const int NT = K >> 6;   // 64-wide k-tiles
    int swz = (l16 & 7);

    // prologue: stage tiles 0 and 1 (barrier drains them — prologue only)
#pragma unroll
    for (int p = 0; p < 2; p++) {
        int ko = p * 64;
#pragma unroll
        for (int j = 0; j < 4; j++)
            gl2lds16(AgS + (size_t)(j * 8) * lda + ko, &As[p][(w * 4 + j) * 512]);
#pragma unroll
        for (int j = 0; j < 2; j++)
            gl2lds16(BgS + (size_t)(j * 8) * ldw + ko, &Bs[p][(w * 2 + j) * 512]);
    }
    __syncthreads();

    int cur = 0;
    for (int t = 0; t < NT; t++) {
        if (t + 2 < NT) {
            int sb = cur + 2; if (sb >= 3) sb -= 3;
            int ko = (t + 2) << 6;
#pragma unroll
            for (int j = 0; j < 4; j++)
                gl2lds16(AgS + (size_t)(j * 8) * lda + ko, &As[sb][(w * 4 + j) * 512]);
#pragma unroll
            for (int j = 0; j < 2; j++)
                gl2lds16(BgS + (size_t)(j * 8) * ldw + ko, &Bs[sb][(w * 2 + j) * 512]);
        }
        const short* Ac = As[cur];
        const short* Bc = Bs[cur];
#pragma unroll
        for (int h = 0; h < 2; h++) {        // two K=32 halves of the 64-tile
            bf16x8 af[4], bfr[4];
#pragma unroll
            for (int mt = 0; mt < 4; mt++) {
                int row = wm * 64 + mt * 16 + l16;
                af[mt] = *(const bf16x8*)&Ac[row * 64 + (((h * 4 + quad) ^ swz)) * 8];
            }
#pragma unroll
            for (int nt = 0; nt < 4; nt++) {
                int row = wn * 64 + nt * 16 + l16;
                bfr[nt] = *(const bf16x8*)&Bc[row * 64 + (((h * 4 + quad) ^ swz)) * 8];
            }
            __builtin_amdgcn_s_setprio(1);
#pragma unroll
            for (int mt = 0; mt < 4; mt++)
#pragma unroll
                for (int nt = 0; nt < 4; nt++)
                    acc[mt][nt] = __builtin_amdgcn_mfma_f32_16x16x32_bf16(af[mt], bfr[nt], acc[mt][nt], 0, 0, 0);
            __builtin_amdgcn_s_setprio(0);
        }
        int ahead = NT - 1 - t;
        if (ahead >= 2)      asm volatile("s_waitcnt vmcnt(6)" ::: "memory");
        else if (ahead == 1) asm volatile("s_waitcnt vmcnt(0)" ::: "memory");
        __builtin_amdgcn_s_barrier();   // t+1 resident everywhere; reads of cur retired
        cur = (cur == 2) ? 0 : cur + 1;
    }

#pragma unroll
    for (int nt = 0; nt < 4; nt++) {
        int c = n0 + wn * 64 + nt * 16 + l16;
        float bv = bias ? bias[boff + c] : 0.f;
#pragma unroll
        for (int mt = 0; mt < 4; mt++) {
#pragma unroll
            for (int reg = 0; reg < 4; reg++) {
                int r = m0 + wm * 64 + mt * 16 + quad * 4 + reg;
                float v = acc[mt][nt][reg] + bv;
                if (ACT == 1) v = 0.5f * v * (1.f + erff(v * 0.70710678118654752f));
                if (ACT == 2) {
                    v += res[(size_t)r * ldres + c];
                    ((float*)out)[(size_t)r * ldo + c] = v;
                } else {
                    ((__hip_bfloat16*)out)[(size_t)r * ldo + c] = __float2bfloat16(v);
                }
            }
        }
    }
}

// ---------------- MFMA flash attention: R5-exact math, 128-key stages -------
__global__ __launch_bounds__(256, 2) void attn_flash(__hip_bfloat16* qkv,
                                                     const short* __restrict__ vt)
{
    __shared__ __align__(16) short Ks[2][2][64 * 64];   // [buf][sub][kvrow][d]
    __shared__ __align__(16) short Vs[2][2][64 * 64];   // [buf][sub][d][kvcol]
    __shared__ __align__(16) short Pl[4][16 * 72];      // wave-private P
    int tid = threadIdx.x;
    int wave = tid >> 6, lane = tid & 63;
    int quad = lane >> 4, l16 = lane & 15;
    int fid = blockIdx.x + 16 * blockIdx.y;          // 0..255
    int h = (fid & 7) * 2 + ((fid >> 3) >> 4);
    int i = (fid >> 3) & 15;
    int b = blockIdx.z;
    int qbs[2]; qbs[0] = i; qbs[1] = 31 - i;
    const size_t rs = 3 * C_;
    __hip_bfloat16* base = qkv + (size_t)b * T_ * rs;
    const __hip_bfloat16* Qb = base + h * D_;
    const __hip_bfloat16* Kb = base + C_ + h * D_;
    const short* Vt = vt + (size_t)(b * H_ + h) * D_ * T_;

    bf16x8 qf[2][2];
#pragma unroll
    for (int tq = 0; tq < 2; tq++) {
        const __hip_bfloat16* qr = Qb + (size_t)(qbs[tq] * 64 + wave * 16 + l16) * rs + quad * 8;
        qf[tq][0] = *(const bf16x8*)qr;
        qf[tq][1] = *(const bf16x8*)(qr + 32);
    }

    f32x4 o[2][4];
    float m[2][4], l[2][4];
#pragma unroll
    for (int tq = 0; tq < 2; tq++)
#pragma unroll
        for (int t = 0; t < 4; t++) {
            o[tq][t] = (f32x4){0.f, 0.f, 0.f, 0.f};
            m[tq][t] = -INFINITY;
            l[tq][t] = 0.f;
        }
    short* Pw = &Pl[wave][0];

    int srow = wave * 16 + (lane >> 3);
    int scg  = ((lane & 7) ^ (lane >> 3)) * 8;
    const __hip_bfloat16* Kg = Kb + (size_t)srow * rs + scg;
    const short*          Vg = Vt + (size_t)srow * T_ + scg;

    int qhi = qbs[1];
    int NS = (qhi >> 1) + 1;
    int swz = (l16 & 7);
    int cur = 0;

#pragma unroll
    for (int sub = 0; sub < 2; sub++)
#pragma unroll
        for (int j = 0; j < 2; j++) {
            gl2lds16(Kg + (size_t)(sub * 64 + j * 8) * rs, &Ks[0][sub][(wave * 2 + j) * 512]);
            gl2lds16(Vg + (size_t)(j * 8) * T_ + sub * 64, &Vs[0][sub][(wave * 2 + j) * 512]);
        }
    __syncthreads();

    for (int s = 0; s < NS; s++) {
        if (s + 1 < NS) {
            int kb = (s + 1) * 128;
#pragma unroll
            for (int sub = 0; sub < 2; sub++)
#pragma unroll
                for (int j = 0; j < 2; j++) {
                    gl2lds16(Kg + (size_t)(kb + sub * 64 + j * 8) * rs, &Ks[cur ^ 1][sub][(wave * 2 + j) * 512]);
                    gl2lds16(Vg + (size_t)(j * 8) * T_ + kb + sub * 64, &Vs[cur ^ 1][sub][(wave * 2 + j) * 512]);
                }
        }
#pragma unroll
        for (int sub = 0; sub < 2; sub++) {
            int kt = 2 * s + sub;
            if (kt > qhi) break;
            const short* Kc = Ks[cur][sub];
            const short* Vc = Vs[cur][sub];
#pragma unroll
            for (int tq = 0; tq < 2; tq++) {
                if (kt > qbs[tq]) continue;
                f32x4 sa[4];
                __builtin_amdgcn_s_setprio(1);
#pragma unroll
                for (int t16 = 0; t16 < 4; t16++) {
                    int row = t16 * 16 + l16;
                    bf16x8 kf0 = *(const bf16x8*)&Kc[row * 64 + ((quad     ^ swz)) * 8];
                    bf16x8 kf1 = *(const bf16x8*)&Kc[row * 64 + (((quad + 4) ^ swz)) * 8];
                    f32x4 sv = (f32x4){0.f, 0.f, 0.f, 0.f};
                    sv = __builtin_amdgcn_mfma_f32_16x16x32_bf16(qf[tq][0], kf0, sv, 0, 0, 0);
                    sv = __builtin_amdgcn_mfma_f32_16x16x32_bf16(qf[tq][1], kf1, sv, 0, 0, 0);
                    sa[t16] = sv;
                }
                __builtin_amdgcn_s_setprio(0);
                bool maskit = (kt == qbs[tq]);
#pragma unroll
                for (int t16 = 0; t16 < 4; t16++) {
#pragma unroll
                    for (int reg = 0; reg < 4; reg++) {
                        float v = sa[t16][reg] * 0.125f;
                        if (maskit) {
                            int keyl = t16 * 16 + l16;
                            int ql = wave * 16 + quad * 4 + reg;
                            if (keyl > ql) v = -3.0e38f;
                        }
                        sa[t16][reg] = v;
                    }
                }
                float mx[4];
#pragma unroll
                for (int reg = 0; reg < 4; reg++)
                    mx[reg] = fmaxf(fmaxf(sa[0][reg], sa[1][reg]), fmaxf(sa[2][reg], sa[3][reg]));
#pragma unroll
                for (int off = 8; off >= 1; off >>= 1)
#pragma unroll
                    for (int reg = 0; reg < 4; reg++)
                        mx[reg] = fmaxf(mx[reg], __shfl_xor(mx[reg], off));
                float alpha[4];
#pragma unroll
                for (int reg = 0; reg < 4; reg++) {
                    float mn = fmaxf(m[tq][reg], mx[reg]);
                    alpha[reg] = __expf(m[tq][reg] - mn);
                    m[tq][reg] = mn;
                }
                float rsum[4] = {0.f, 0.f, 0.f, 0.f};
#pragma unroll
                for (int t16 = 0; t16 < 4; t16++) {
#pragma unroll
                    for (int reg = 0; reg < 4; reg++) {
                        float p = __expf(sa[t16][reg] - m[tq][reg]);
                        rsum[reg] += p;
                        Pw[(quad * 4 + reg) * 72 + t16 * 16 + l16] = f2bfraw(p);
                    }
                }
#pragma unroll
                for (int off = 8; off >= 1; off >>= 1)
#pragma unroll
                    for (int reg = 0; reg < 4; reg++)
                        rsum[reg] += __shfl_xor(rsum[reg], off);
#pragma unroll
                for (int reg = 0; reg < 4; reg++)
                    l[tq][reg] = l[tq][reg] * alpha[reg] + rsum[reg];
#pragma unroll
                for (int t = 0; t < 4; t++)
#pragma unroll
                    for (int reg = 0; reg < 4; reg++)
                        o[tq][t][reg] *= alpha[reg];
                __builtin_amdgcn_s_setprio(1);
#pragma unroll
                for (int chunk = 0; chunk < 2; chunk++) {
                    bf16x8 pf = *(const bf16x8*)&Pw[l16 * 72 + chunk * 32 + quad * 8];
#pragma unroll
                    for (int dt = 0; dt < 4; dt++) {
                        int row = dt * 16 + l16;
                        bf16x8 vf = *(const bf16x8*)&Vc[row * 64 + (((chunk * 4 + quad) ^ swz)) * 8];
                        o[tq][dt] = __builtin_amdgcn_mfma_f32_16x16x32_bf16(pf, vf, o[tq][dt], 0, 0, 0);
                    }
                }
                __builtin_amdgcn_s_setprio(0);
            }
        }
        __syncthreads();
        cur ^= 1;
    }

#pragma unroll
    for (int tq = 0; tq < 2; tq++) {
#pragma unroll
        for (int dt = 0; dt < 4; dt++) {
#pragma unroll
            for (int reg = 0; reg < 4; reg++) {
                int r = qbs[tq] * 64 + wave * 16 + quad * 4 + reg;
                float v = o[tq][dt][reg] / l[tq][reg];
                base[(size_t)r * rs + h * D_ + dt * 16 + l16] = __float2bfloat16(v);
            }
        }
    }
}

extern "C" void kernel_launch(void* const* d_in, const int* in_sizes, int n_in,
                              void* d_out, int out_size, void* d_ws, size_t ws_size,
                              hipStream_t stream)
{
    const float* x     = (const float*)d_in[0];
    const float* ln1_g = (const float*)d_in[1];
    const float* ln1_b = (const float*)d_in[2];
    const float* qkv_w = (const float*)d_in[3];
    const float* qkv_b = (const float*)d_in[4];
    const float* out_w = (const float*)d_in[5];
    const float* out_b = (const float*)d_in[6];
    const float* ln2_g = (const float*)d_in[7];
    const float* ln2_b = (const float*)d_in[8];
    const float* ff1_w = (const float*)d_in[9];
    const float* ff1_b = (const float*)d_in[10];
    const float* ff2_w = (const float*)d_in[11];
    const float* ff2_b = (const float*)d_in[12];

    // ws (48 MiB): [0,24M) qkv bf16 [4096][3072]
    //   Q cols 0..1023: q -> attn-out -> hbuf2 (LN2 out, live whole FF phase)
    //   K+V cols 1024..3071: k,v -> ff1 act chunk (width 2048, per chunk)
    //   [24M,30M) qkvW^T; [30M,32M) outW^T; [32M,40M) ff1W^T; [40M,48M) ff2W^T
    // d_out (16 MiB fp32 [4096][1024]):
    //   phase 1: [0,8M) hbuf1 bf16 (LN1 out, dead after QKV GEMM)
    //   phase 1.5: [0,8M) Vt bf16 [B*H][64 d][2048 t] (dead after attention)
    //   phase 2: x1 residual fp32 (out-proj), FF2 accumulates in place.
    char* ws = (char*)d_ws;
    __hip_bfloat16* qkv = (__hip_bfloat16*)ws;
    short* qkvwT = (short*)(ws + 25165824);
    short* outwT = (short*)(ws + 31457280);
    short* ff1wT = (short*)(ws + 33554432);
    short* ff2wT = (short*)(ws + 41943040);
    __hip_bfloat16* hbuf2 = qkv;                           // Q slots, ld 3072
    __hip_bfloat16* act   = qkv + 1024;                    // K+V slots, ld 3072
    __hip_bfloat16* hbuf1 = (__hip_bfloat16*)d_out;        // ld 1024 (bf16)
    float* x1 = (float*)d_out;                             // fp32, ld 1024
    short* vtbuf = (short*)d_out;                          // bf16 Vt, 8 MiB

    // 0) weight convert+transpose (fp32 -> bf16 W^T), single launch
    wconv_all<<<3072, 256, 0, stream>>>(qkv_w, qkvwT, out_w, outwT,
                                        ff1_w, ff1wT, ff2_w, ff2wT);

    // 1) LN1(x) -> hbuf1 (d_out scratch, bf16)
    ln_fused<<<BT_, 256, 0, stream>>>(x, C_, ln1_g, ln1_b, hbuf1, C_);
    // 2) QKV: hbuf1 @ qkv_w + qkv_b -> qkv (hbuf1 dead after)
    gemm8p<0><<<dim3(3 * C_ / 128, BT_ / 256), 512, 0, stream>>>(
        hbuf1, C_, qkvwT, C_, 0, 0, qkv_b, 0, nullptr, 0, qkv, 3 * C_, C_);
    // 2.5) transpose V into Vt (d_out scratch; hbuf1 dead)
    v_transpose<<<dim3(T_ / 64, H_, B_), 256, 0, stream>>>(qkv, vtbuf);
    // 3) attention -> Q slots (paired q-tiles, 128-key pipelined LDS stages)
    attn_flash<<<dim3(16, H_, B_), 256, 0, stream>>>(qkv, vtbuf);
    // 4) out proj + residual(x) -> x1 = d_out (fp32); Q slots + Vt dead after
    gemm8p<2><<<dim3(C_ / 128, BT_ / 256), 512, 0, stream>>>(
        qkv, 3 * C_, outwT, C_, 0, 0, out_b, 0, x, C_, x1, C_, C_);
    // 5) LN2(x1) -> hbuf2 (Q slots)
    ln_fused<<<BT_, 256, 0, stream>>>(x1, C_, ln2_g, ln2_b, hbuf2, 3 * C_);
    // 6) FF in two 2048-wide chunks; act in K+V slots; FF2 accumulates into
    //    d_out in place.
    for (int f = 0; f < 2; f++) {
        gemm8p<1><<<dim3(2048 / 128, BT_ / 256), 512, 0, stream>>>(
            hbuf2, 3 * C_, ff1wT, C_, f * 2048, 0, ff1_b, f * 2048,
            nullptr, 0, act, 3 * C_, C_);
        gemm8p<2><<<dim3(C_ / 128, BT_ / 256), 512, 0, stream>>>(
            act, 3 * C_, ff2wT, F_, 0, f * 2048, (f == 0 ? ff2_b : nullptr), 0,
            x1, C_, x1, C_, 2048);
    }
}

// Round 10
// 417.021 us; speedup vs baseline: 1.1343x; 1.1343x over previous
//
#include <hip/hip_runtime.h>
#include <hip/hip_bf16.h>
#include <math.h>

#define B_ 2
#define T_ 2048
#define C_ 1024
#define H_ 16
#define D_ 64
#define F_ 4096
#define BT_ (B_*T_)

typedef __attribute__((ext_vector_type(8))) short bf16x8;
typedef __attribute__((ext_vector_type(4))) float f32x4;

__device__ __forceinline__ float bfraw2f(unsigned int u){
    union { unsigned int i; float f; } c; c.i = u << 16; return c.f;
}
// f32 -> bf16 raw bits, round-to-nearest-even
__device__ __forceinline__ short f2bfraw(float f){
    union { float f; unsigned int i; } c; c.f = f;
    unsigned int u = c.i;
    u += 0x7fffu + ((u >> 16) & 1u);
    return (short)(u >> 16);
}
// async global->LDS, 16B per lane; LDS dest = wave-uniform base + lane*16
__device__ __forceinline__ void gl2lds16(const void* g, void* l) {
    __builtin_amdgcn_global_load_lds(
        (const __attribute__((address_space(1))) unsigned int*)g,
        (__attribute__((address_space(3))) unsigned int*)l,
        16, 0, 0);
}

// ------- merged weight convert + transpose, 1D flattened grid --------------
// 3072 blocks total: [0,768) qkv, [768,1024) out, [1024,2048) ff1, [2048,3072) ff2.
__global__ __launch_bounds__(256) void wconv_all(const float* qkv_w, short* qkvwT,
                                                 const float* out_w, short* outwT,
                                                 const float* ff1_w, short* ff1wT,
                                                 const float* ff2_w, short* ff2wT)
{
    int id = blockIdx.x;
    const float* W; short* Wt; int K, N;
    if (id < 768)       { W = qkv_w; Wt = qkvwT; K = C_; N = 3 * C_; }
    else if (id < 1024) { id -= 768;  W = out_w; Wt = outwT; K = C_; N = C_; }
    else if (id < 2048) { id -= 1024; W = ff1_w; Wt = ff1wT; K = C_; N = F_; }
    else                { id -= 2048; W = ff2_w; Wt = ff2wT; K = F_; N = C_; }
    int ntile = N >> 6;
    int n0 = (id % ntile) * 64, k0 = (id / ntile) * 64;

    __shared__ short tile[64][65];
    int t = threadIdx.x;
#pragma unroll
    for (int i = 0; i < 4; i++) {
        int idx = t + i * 256;
        int r = idx >> 4, c4 = (idx & 15) * 4;
        float4 u = *(const float4*)(W + (size_t)(k0 + r) * N + n0 + c4);
        tile[c4 + 0][r] = f2bfraw(u.x);
        tile[c4 + 1][r] = f2bfraw(u.y);
        tile[c4 + 2][r] = f2bfraw(u.z);
        tile[c4 + 3][r] = f2bfraw(u.w);
    }
    __syncthreads();
#pragma unroll
    for (int i = 0; i < 2; i++) {
        int idx = t + i * 256;
        int r = idx >> 3, c8 = (idx & 7) * 8;
        short v[8];
#pragma unroll
        for (int u8 = 0; u8 < 8; u8++) v[u8] = tile[r][c8 + u8];
        *(uint4*)(Wt + (size_t)(n0 + r) * K + k0 + c8) = *(const uint4*)v;
    }
}

// ---------------- fused LayerNorm (fp32 in, bf16 out) ----------------
__global__ __launch_bounds__(256) void ln_fused(const float* __restrict__ x, int ldx,
                                                const float* __restrict__ g,
                                                const float* __restrict__ b,
                                                __hip_bfloat16* out, int ldo)
{
    __shared__ float sm1[4], sm2[4];
    __shared__ float smu, srs;
    int row = blockIdx.x, t = threadIdx.x;
    const float* xr = x + (size_t)row * ldx;
    float v[4]; float s = 0.f, ss = 0.f;
#pragma unroll
    for (int i = 0; i < 4; i++) {
        float f = xr[t + i * 256];
        v[i] = f; s += f; ss += f * f;
    }
#pragma unroll
    for (int off = 32; off >= 1; off >>= 1) {
        s  += __shfl_xor(s,  off);
        ss += __shfl_xor(ss, off);
    }
    int wave = t >> 6, lane = t & 63;
    if (!lane) { sm1[wave] = s; sm2[wave] = ss; }
    __syncthreads();
    if (t == 0) {
        s  = sm1[0] + sm1[1] + sm1[2] + sm1[3];
        ss = sm2[0] + sm2[1] + sm2[2] + sm2[3];
        float mu  = s * (1.f / C_);
        float var = ss * (1.f / C_) - mu * mu;
        if (var < 0.f) var = 0.f;
        smu = mu; srs = rsqrtf(var + 1e-5f);
    }
    __syncthreads();
    float mu = smu, rs = srs;
#pragma unroll
    for (int i = 0; i < 4; i++) {
        int c = t + i * 256;
        out[(size_t)row * ldo + c] = __float2bfloat16((v[i] - mu) * rs * g[c] + b[c]);
    }
}

// ---------------- 128x128 MFMA GEMM, 3-deep counted-vmcnt pipeline ----------
// out = A[M,K](bf16) @ Wt[N,K]^T + bias. Out bf16.
// ACT: 0 = plain; 1 = GELU; 3 = QKV-mode: cols < 2048 (Q,K) written normally,
// cols >= 2048 (V) written ONLY transposed into vtout[b*H+h][d][t]
// (n-blocks are 128-wide so the branch is block-uniform).
// koff applies to Wt ONLY; A reads k from 0.
template<int ACT>
__global__ __launch_bounds__(256) void gemm128(
    const __hip_bfloat16* A, int lda,
    const short* Wt, int ldw, int noff, int koff,
    const float* __restrict__ bias, int boff,
    void* out, int ldo,
    short* vtout,
    int K)
{
    __shared__ __align__(16) short As[3][128 * 32];
    __shared__ __align__(16) short Bs[3][128 * 32];
    int tid = threadIdx.x;
    int w = tid >> 6, lane = tid & 63;
    int quad = lane >> 4, l16 = lane & 15;
    int wm = w >> 1, wn = w & 1;
    int m0 = blockIdx.y * 128, n0 = blockIdx.x * 128;
    int lr = lane >> 2, lk = (lane & 3) * 8;

    const __hip_bfloat16* Ag = A + (size_t)(m0 + w * 32 + lr) * lda + lk;
    const short*          Bg = Wt + (size_t)(noff + n0 + w * 32 + lr) * ldw + koff + lk;

    f32x4 acc[4][4];
#pragma unroll
    for (int i = 0; i < 4; i++)
#pragma unroll
        for (int j = 0; j < 4; j++) acc[i][j] = (f32x4){0.f, 0.f, 0.f, 0.f};

    const int NT = K >> 5;
    // prologue: stage tile 0 -> buf0, tile 1 -> buf1
    {
        gl2lds16(Ag,            &As[0][(w * 32) * 32]);
        gl2lds16(Ag + 16 * lda, &As[0][(w * 32 + 16) * 32]);
        gl2lds16(Bg,            &Bs[0][(w * 32) * 32]);
        gl2lds16(Bg + 16 * ldw, &Bs[0][(w * 32 + 16) * 32]);
        if (NT > 1) {
            gl2lds16(Ag + 32,            &As[1][(w * 32) * 32]);
            gl2lds16(Ag + 16 * lda + 32, &As[1][(w * 32 + 16) * 32]);
            gl2lds16(Bg + 32,            &Bs[1][(w * 32) * 32]);
            gl2lds16(Bg + 16 * ldw + 32, &Bs[1][(w * 32 + 16) * 32]);
        }
    }

    int cur = 0;   // buffer holding tile t (cur == t % 3)
    for (int t = 0; t < NT; t++) {
        if (t + 2 < NT) {
            int sb = cur + 2; if (sb >= 3) sb -= 3;
            int ko = (t + 2) << 5;
            gl2lds16(Ag + ko,            &As[sb][(w * 32) * 32]);
            gl2lds16(Ag + 16 * lda + ko, &As[sb][(w * 32 + 16) * 32]);
            gl2lds16(Bg + ko,            &Bs[sb][(w * 32) * 32]);
            gl2lds16(Bg + 16 * ldw + ko, &Bs[sb][(w * 32 + 16) * 32]);
        }
        int ahead = NT - 1 - t;
        if (ahead >= 2)      asm volatile("s_waitcnt vmcnt(8)" ::: "memory");
        else if (ahead == 1) asm volatile("s_waitcnt vmcnt(4)" ::: "memory");
        else                 asm volatile("s_waitcnt vmcnt(0)" ::: "memory");
        __builtin_amdgcn_s_barrier();
        __builtin_amdgcn_sched_barrier(0);

        bf16x8 af[4], bfr[4];
#pragma unroll
        for (int mt = 0; mt < 4; mt++)
            af[mt] = *(const bf16x8*)&As[cur][(wm * 64 + mt * 16 + l16) * 32 + quad * 8];
#pragma unroll
        for (int nt = 0; nt < 4; nt++)
            bfr[nt] = *(const bf16x8*)&Bs[cur][(wn * 64 + nt * 16 + l16) * 32 + quad * 8];
#pragma unroll
        for (int mt = 0; mt < 4; mt++)
#pragma unroll
            for (int nt = 0; nt < 4; nt++)
                acc[mt][nt] = __builtin_amdgcn_mfma_f32_16x16x32_bf16(af[mt], bfr[nt], acc[mt][nt], 0, 0, 0);

        __builtin_amdgcn_sched_barrier(0);
        __builtin_amdgcn_s_barrier();   // reads of buf cur retired before overwrite
        cur = (cur == 2) ? 0 : cur + 1;
    }

#pragma unroll
    for (int nt = 0; nt < 4; nt++) {
        int c = n0 + wn * 64 + nt * 16 + l16;
        float bv = bias ? bias[boff + c] : 0.f;
        if (ACT == 3 && c >= 2048) {
            // V output: write transposed into vtout[b*H+h][d][t]
            int hh = (c - 2048) >> 6, d = (c - 2048) & 63;
#pragma unroll
            for (int mt = 0; mt < 4; mt++) {
                int r0 = m0 + wm * 64 + mt * 16 + quad * 4;
                short vals[4];
#pragma unroll
                for (int reg = 0; reg < 4; reg++)
                    vals[reg] = f2bfraw(acc[mt][nt][reg] + bv);
                int bb = r0 >> 11, tt = r0 & 2047;
                *(uint2*)(vtout + ((size_t)(bb * H_ + hh) * D_ + d) * T_ + tt)
                    = *(const uint2*)vals;
            }
        } else {
#pragma unroll
            for (int mt = 0; mt < 4; mt++) {
#pragma unroll
                for (int reg = 0; reg < 4; reg++) {
                    int r = m0 + wm * 64 + mt * 16 + quad * 4 + reg;
                    float v = acc[mt][nt][reg] + bv;
                    if (ACT == 1) v = 0.5f * v * (1.f + erff(v * 0.70710678118654752f));
                    ((__hip_bfloat16*)out)[(size_t)r * ldo + c] = __float2bfloat16(v);
                }
            }
        }
    }
}

// ------- 128Mx64N MFMA GEMM, fp32 out + residual, 3-deep counted-vmcnt ------
// Wave-tile 64Mx32N: 6 ds_read : 8 MFMA per k-step. 36 KB LDS.
// out[r][c] = A@Wt^T + (bias?) + res[r][c] (res may alias out: in-place RMW).
// koff applies to Wt ONLY; A reads k from 0.
__global__ __launch_bounds__(256) void gemm64n(
    const __hip_bfloat16* A, int lda,
    const short* Wt, int ldw, int koff,
    const float* __restrict__ bias,
    const float* res, int ldres,
    float* out, int ldo,
    int K)
{
    __shared__ __align__(16) short As[3][128 * 32];   // [m][k]
    __shared__ __align__(16) short Bs[3][64 * 32];    // [n][k]
    int tid = threadIdx.x;
    int w = tid >> 6, lane = tid & 63;
    int quad = lane >> 4, l16 = lane & 15;
    int wm = w >> 1, wn = w & 1;                   // 2x2 wave grid
    int m0 = blockIdx.y * 128, n0 = blockIdx.x * 64;
    int lr = lane >> 2, lk = (lane & 3) * 8;

    const __hip_bfloat16* Ag = A + (size_t)(m0 + w * 32 + lr) * lda + lk;          // no koff
    const short*          Bg = Wt + (size_t)(n0 + w * 16 + lr) * ldw + koff + lk;  // koff here only

    f32x4 acc[4][2];
#pragma unroll
    for (int i = 0; i < 4; i++)
#pragma unroll
        for (int j = 0; j < 2; j++) acc[i][j] = (f32x4){0.f, 0.f, 0.f, 0.f};

    const int NT = K >> 5;
    // prologue: stage tile 0 -> buf0, tile 1 -> buf1
    {
        gl2lds16(Ag,            &As[0][(w * 32) * 32]);
        gl2lds16(Ag + 16 * lda, &As[0][(w * 32 + 16) * 32]);
        gl2lds16(Bg,            &Bs[0][(w * 16) * 32]);
        if (NT > 1) {
            gl2lds16(Ag + 32,            &As[1][(w * 32) * 32]);
            gl2lds16(Ag + 16 * lda + 32, &As[1][(w * 32 + 16) * 32]);
            gl2lds16(Bg + 32,            &Bs[1][(w * 16) * 32]);
        }
    }

    int cur = 0;
    for (int t = 0; t < NT; t++) {
        if (t + 2 < NT) {
            int sb = cur + 2; if (sb >= 3) sb -= 3;
            int ko = (t + 2) << 5;
            gl2lds16(Ag + ko,            &As[sb][(w * 32) * 32]);
            gl2lds16(Ag + 16 * lda + ko, &As[sb][(w * 32 + 16) * 32]);
            gl2lds16(Bg + ko,            &Bs[sb][(w * 16) * 32]);
        }
        int ahead = NT - 1 - t;
        if (ahead >= 2)      asm volatile("s_waitcnt vmcnt(6)" ::: "memory");
        else if (ahead == 1) asm volatile("s_waitcnt vmcnt(3)" ::: "memory");
        else                 asm volatile("s_waitcnt vmcnt(0)" ::: "memory");
        __builtin_amdgcn_s_barrier();
        __builtin_amdgcn_sched_barrier(0);

        bf16x8 af[4], bfr[2];
#pragma unroll
        for (int mt = 0; mt < 4; mt++)
            af[mt] = *(const bf16x8*)&As[cur][(wm * 64 + mt * 16 + l16) * 32 + quad * 8];
#pragma unroll
        for (int nt = 0; nt < 2; nt++)
            bfr[nt] = *(const bf16x8*)&Bs[cur][(wn * 32 + nt * 16 + l16) * 32 + quad * 8];
#pragma unroll
        for (int mt = 0; mt < 4; mt++)
#pragma unroll
            for (int nt = 0; nt < 2; nt++)
                acc[mt][nt] = __builtin_amdgcn_mfma_f32_16x16x32_bf16(af[mt], bfr[nt], acc[mt][nt], 0, 0, 0);

        __builtin_amdgcn_sched_barrier(0);
        __builtin_amdgcn_s_barrier();
        cur = (cur == 2) ? 0 : cur + 1;
    }

#pragma unroll
    for (int nt = 0; nt < 2; nt++) {
        int c = n0 + wn * 32 + nt * 16 + l16;
        float bv = bias ? bias[c] : 0.f;
#pragma unroll
        for (int mt = 0; mt < 4; mt++) {
#pragma unroll
            for (int reg = 0; reg < 4; reg++) {
                int r = m0 + wm * 64 + mt * 16 + quad * 4 + reg;
                float v = acc[mt][nt][reg] + bv + res[(size_t)r * ldres + c];
                out[(size_t)r * ldo + c] = v;
            }
        }
    }
}

// ---------------- MFMA flash attention: R5-exact math, 128-key stages -------
__global__ __launch_bounds__(256, 2) void attn_flash(__hip_bfloat16* qkv,
                                                     const short* __restrict__ vt)
{
    __shared__ __align__(16) short Ks[2][2][64 * 64];   // [buf][sub][kvrow][d]
    __shared__ __align__(16) short Vs[2][2][64 * 64];   // [buf][sub][d][kvcol]
    __shared__ __align__(16) short Pl[4][16 * 72];      // wave-private P
    int tid = threadIdx.x;
    int wave = tid >> 6, lane = tid & 63;
    int quad = lane >> 4, l16 = lane & 15;
    int fid = blockIdx.x + 16 * blockIdx.y;          // 0..255
    int h = (fid & 7) * 2 + ((fid >> 3) >> 4);
    int i = (fid >> 3) & 15;
    int b = blockIdx.z;
    int qbs[2]; qbs[0] = i; qbs[1] = 31 - i;
    const size_t rs = 3 * C_;
    __hip_bfloat16* base = qkv + (size_t)b * T_ * rs;
    const __hip_bfloat16* Qb = base + h * D_;
    const __hip_bfloat16* Kb = base + C_ + h * D_;
    const short* Vt = vt + (size_t)(b * H_ + h) * D_ * T_;

    bf16x8 qf[2][2];
#pragma unroll
    for (int tq = 0; tq < 2; tq++) {
        const __hip_bfloat16* qr = Qb + (size_t)(qbs[tq] * 64 + wave * 16 + l16) * rs + quad * 8;
        qf[tq][0] = *(const bf16x8*)qr;
        qf[tq][1] = *(const bf16x8*)(qr + 32);
    }

    f32x4 o[2][4];
    float m[2][4], l[2][4];
#pragma unroll
    for (int tq = 0; tq < 2; tq++)
#pragma unroll
        for (int t = 0; t < 4; t++) {
            o[tq][t] = (f32x4){0.f, 0.f, 0.f, 0.f};
            m[tq][t] = -INFINITY;
            l[tq][t] = 0.f;
        }
    short* Pw = &Pl[wave][0];

    int srow = wave * 16 + (lane >> 3);
    int scg  = ((lane & 7) ^ (lane >> 3)) * 8;
    const __hip_bfloat16* Kg = Kb + (size_t)srow * rs + scg;
    const short*          Vg = Vt + (size_t)srow * T_ + scg;

    int qhi = qbs[1];
    int NS = (qhi >> 1) + 1;
    int swz = (l16 & 7);
    int cur = 0;

#pragma unroll
    for (int sub = 0; sub < 2; sub++)
#pragma unroll
        for (int j = 0; j < 2; j++) {
            gl2lds16(Kg + (size_t)(sub * 64 + j * 8) * rs, &Ks[0][sub][(wave * 2 + j) * 512]);
            gl2lds16(Vg + (size_t)(j * 8) * T_ + sub * 64, &Vs[0][sub][(wave * 2 + j) * 512]);
        }
    __syncthreads();

    for (int s = 0; s < NS; s++) {
        if (s + 1 < NS) {
            int kb = (s + 1) * 128;
#pragma unroll
            for (int sub = 0; sub < 2; sub++)
#pragma unroll
                for (int j = 0; j < 2; j++) {
                    gl2lds16(Kg + (size_t)(kb + sub * 64 + j * 8) * rs, &Ks[cur ^ 1][sub][(wave * 2 + j) * 512]);
                    gl2lds16(Vg + (size_t)(j * 8) * T_ + kb + sub * 64, &Vs[cur ^ 1][sub][(wave * 2 + j) * 512]);
                }
        }
#pragma unroll
        for (int sub = 0; sub < 2; sub++) {
            int kt = 2 * s + sub;
            if (kt > qhi) break;
            const short* Kc = Ks[cur][sub];
            const short* Vc = Vs[cur][sub];
#pragma unroll
            for (int tq = 0; tq < 2; tq++) {
                if (kt > qbs[tq]) continue;
                f32x4 sa[4];
                __builtin_amdgcn_s_setprio(1);
#pragma unroll
                for (int t16 = 0; t16 < 4; t16++) {
                    int row = t16 * 16 + l16;
                    bf16x8 kf0 = *(const bf16x8*)&Kc[row * 64 + ((quad     ^ swz)) * 8];
                    bf16x8 kf1 = *(const bf16x8*)&Kc[row * 64 + (((quad + 4) ^ swz)) * 8];
                    f32x4 sv = (f32x4){0.f, 0.f, 0.f, 0.f};
                    sv = __builtin_amdgcn_mfma_f32_16x16x32_bf16(qf[tq][0], kf0, sv, 0, 0, 0);
                    sv = __builtin_amdgcn_mfma_f32_16x16x32_bf16(qf[tq][1], kf1, sv, 0, 0, 0);
                    sa[t16] = sv;
                }
                __builtin_amdgcn_s_setprio(0);
                bool maskit = (kt == qbs[tq]);
#pragma unroll
                for (int t16 = 0; t16 < 4; t16++) {
#pragma unroll
                    for (int reg = 0; reg < 4; reg++) {
                        float v = sa[t16][reg] * 0.125f;
                        if (maskit) {
                            int keyl = t16 * 16 + l16;
                            int ql = wave * 16 + quad * 4 + reg;
                            if (keyl > ql) v = -3.0e38f;
                        }
                        sa[t16][reg] = v;
                    }
                }
                float mx[4];
#pragma unroll
                for (int reg = 0; reg < 4; reg++)
                    mx[reg] = fmaxf(fmaxf(sa[0][reg], sa[1][reg]), fmaxf(sa[2][reg], sa[3][reg]));
#pragma unroll
                for (int off = 8; off >= 1; off >>= 1)
#pragma unroll
                    for (int reg = 0; reg < 4; reg++)
                        mx[reg] = fmaxf(mx[reg], __shfl_xor(mx[reg], off));
                float alpha[4];
#pragma unroll
                for (int reg = 0; reg < 4; reg++) {
                    float mn = fmaxf(m[tq][reg], mx[reg]);
                    alpha[reg] = __expf(m[tq][reg] - mn);
                    m[tq][reg] = mn;
                }
                float rsum[4] = {0.f, 0.f, 0.f, 0.f};
#pragma unroll
                for (int t16 = 0; t16 < 4; t16++) {
#pragma unroll
                    for (int reg = 0; reg < 4; reg++) {
                        float p = __expf(sa[t16][reg] - m[tq][reg]);
                        rsum[reg] += p;
                        Pw[(quad * 4 + reg) * 72 + t16 * 16 + l16] = f2bfraw(p);
                    }
                }
#pragma unroll
                for (int off = 8; off >= 1; off >>= 1)
#pragma unroll
                    for (int reg = 0; reg < 4; reg++)
                        rsum[reg] += __shfl_xor(rsum[reg], off);
#pragma unroll
                for (int reg = 0; reg < 4; reg++)
                    l[tq][reg] = l[tq][reg] * alpha[reg] + rsum[reg];
#pragma unroll
                for (int t = 0; t < 4; t++)
#pragma unroll
                    for (int reg = 0; reg < 4; reg++)
                        o[tq][t][reg] *= alpha[reg];
                __builtin_amdgcn_s_setprio(1);
#pragma unroll
                for (int chunk = 0; chunk < 2; chunk++) {
                    bf16x8 pf = *(const bf16x8*)&Pw[l16 * 72 + chunk * 32 + quad * 8];
#pragma unroll
                    for (int dt = 0; dt < 4; dt++) {
                        int row = dt * 16 + l16;
                        bf16x8 vf = *(const bf16x8*)&Vc[row * 64 + (((chunk * 4 + quad) ^ swz)) * 8];
                        o[tq][dt] = __builtin_amdgcn_mfma_f32_16x16x32_bf16(pf, vf, o[tq][dt], 0, 0, 0);
                    }
                }
                __builtin_amdgcn_s_setprio(0);
            }
        }
        __syncthreads();
        cur ^= 1;
    }

#pragma unroll
    for (int tq = 0; tq < 2; tq++) {
#pragma unroll
        for (int dt = 0; dt < 4; dt++) {
#pragma unroll
            for (int reg = 0; reg < 4; reg++) {
                int r = qbs[tq] * 64 + wave * 16 + quad * 4 + reg;
                float v = o[tq][dt][reg] / l[tq][reg];
                base[(size_t)r * rs + h * D_ + dt * 16 + l16] = __float2bfloat16(v);
            }
        }
    }
}

extern "C" void kernel_launch(void* const* d_in, const int* in_sizes, int n_in,
                              void* d_out, int out_size, void* d_ws, size_t ws_size,
                              hipStream_t stream)
{
    const float* x     = (const float*)d_in[0];
    const float* ln1_g = (const float*)d_in[1];
    const float* ln1_b = (const float*)d_in[2];
    const float* qkv_w = (const float*)d_in[3];
    const float* qkv_b = (const float*)d_in[4];
    const float* out_w = (const float*)d_in[5];
    const float* out_b = (const float*)d_in[6];
    const float* ln2_g = (const float*)d_in[7];
    const float* ln2_b = (const float*)d_in[8];
    const float* ff1_w = (const float*)d_in[9];
    const float* ff1_b = (const float*)d_in[10];
    const float* ff2_w = (const float*)d_in[11];
    const float* ff2_b = (const float*)d_in[12];

    // ws (48 MiB): [0,24M) qkv bf16 [4096][3072]
    //   Q cols 0..1023: q -> attn-out -> hbuf2 (LN2 out, live whole FF phase)
    //   K cols 1024..2047; V cols 2048..3071 UNUSED (V goes straight to vtbuf
    //   from the QKV GEMM epilogue); K+V slots reused as ff1 act chunk later.
    //   [24M,30M) qkvW^T; [30M,32M) outW^T; [32M,40M) ff1W^T; [40M,48M) ff2W^T
    // d_out (16 MiB fp32 [4096][1024]):
    //   phase 1: [0,8M) hbuf1 bf16 (LN1 out, A operand of QKV GEMM);
    //            [8M,16M) vtbuf bf16 [B*H][64 d][2048 t] (written by QKV GEMM
    //            epilogue — no overlap with hbuf1; dead after attention)
    //   phase 2: x1 residual fp32 (out-proj), FF2 accumulates in place.
    char* ws = (char*)d_ws;
    __hip_bfloat16* qkv = (__hip_bfloat16*)ws;
    short* qkvwT = (short*)(ws + 25165824);
    short* outwT = (short*)(ws + 31457280);
    short* ff1wT = (short*)(ws + 33554432);
    short* ff2wT = (short*)(ws + 41943040);
    __hip_bfloat16* hbuf2 = qkv;                           // Q slots, ld 3072
    __hip_bfloat16* act   = qkv + 1024;                    // K+V slots, ld 3072
    __hip_bfloat16* hbuf1 = (__hip_bfloat16*)d_out;        // ld 1024 (bf16)
    float* x1 = (float*)d_out;                             // fp32, ld 1024
    short* vtbuf = (short*)d_out + 4194304;                // bf16 Vt at [8M,16M)

    // 0) weight convert+transpose (fp32 -> bf16 W^T), single launch
    wconv_all<<<3072, 256, 0, stream>>>(qkv_w, qkvwT, out_w, outwT,
                                        ff1_w, ff1wT, ff2_w, ff2wT);

    // 1) LN1(x) -> hbuf1 (d_out scratch, bf16)
    ln_fused<<<BT_, 256, 0, stream>>>(x, C_, ln1_g, ln1_b, hbuf1, C_);
    // 2) QKV: hbuf1 @ qkv_w + qkv_b -> Q,K into qkv; V transposed into vtbuf
    gemm128<3><<<dim3(3 * C_ / 128, BT_ / 128), 256, 0, stream>>>(
        hbuf1, C_, qkvwT, C_, 0, 0, qkv_b, 0, qkv, 3 * C_, vtbuf, C_);
    // 3) attention -> Q slots (paired q-tiles, 128-key pipelined LDS stages)
    attn_flash<<<dim3(16, H_, B_), 256, 0, stream>>>(qkv, vtbuf);
    // 4) out proj + residual(x) -> x1 = d_out (fp32); Q slots + Vt dead after
    gemm64n<<<dim3(C_ / 64, BT_ / 128), 256, 0, stream>>>(
        qkv, 3 * C_, outwT, C_, 0, out_b, x, C_, x1, C_, C_);
    // 5) LN2(x1) -> hbuf2 (Q slots)
    ln_fused<<<BT_, 256, 0, stream>>>(x1, C_, ln2_g, ln2_b, hbuf2, 3 * C_);
    // 6) FF in two 2048-wide chunks; act in K+V slots; FF2 accumulates into
    //    d_out in place.
    for (int f = 0; f < 2; f++) {
        gemm128<1><<<dim3(2048 / 128, BT_ / 128), 256, 0, stream>>>(
            hbuf2, 3 * C_, ff1wT, C_, f * 2048, 0, ff1_b, f * 2048,
            act, 3 * C_, nullptr, C_);
        gemm64n<<<dim3(C_ / 64, BT_ / 128), 256, 0, stream>>>(
            act, 3 * C_, ff2wT, F_, f * 2048, (f == 0 ? ff2_b : nullptr),
            x1, C_, x1, C_, 2048);
    }
}

// Round 12
// 412.767 us; speedup vs baseline: 1.1460x; 1.0103x over previous
//
#include <hip/hip_runtime.h>
#include <hip/hip_bf16.h>
#include <math.h>

#define B_ 2
#define T_ 2048
#define C_ 1024
#define H_ 16
#define D_ 64
#define F_ 4096
#define BT_ (B_*T_)

typedef __attribute__((ext_vector_type(8))) short bf16x8;
typedef __attribute__((ext_vector_type(4))) float f32x4;

__device__ __forceinline__ float bfraw2f(unsigned int u){
    union { unsigned int i; float f; } c; c.i = u << 16; return c.f;
}
// f32 -> bf16 raw bits, round-to-nearest-even
__device__ __forceinline__ short f2bfraw(float f){
    union { float f; unsigned int i; } c; c.f = f;
    unsigned int u = c.i;
    u += 0x7fffu + ((u >> 16) & 1u);
    return (short)(u >> 16);
}
// async global->LDS, 16B per lane; LDS dest = wave-uniform base + lane*16
__device__ __forceinline__ void gl2lds16(const void* g, void* l) {
    __builtin_amdgcn_global_load_lds(
        (const __attribute__((address_space(1))) unsigned int*)g,
        (__attribute__((address_space(3))) unsigned int*)l,
        16, 0, 0);
}

// ------- merged weight convert + LN1, 1D flattened grid --------------------
// blocks [0,3072): weight convert+transpose:
//   [0,768) qkv, [768,1024) out, [1024,2048) ff1, [2048,3072) ff2.
// blocks [3072,7168): LN1 row (id-3072) : x fp32 -> hbuf1 bf16 (ld C_).
__global__ __launch_bounds__(256) void wconv_ln1(
    const float* qkv_w, short* qkvwT,
    const float* out_w, short* outwT,
    const float* ff1_w, short* ff1wT,
    const float* ff2_w, short* ff2wT,
    const float* __restrict__ x,
    const float* __restrict__ ln1_g,
    const float* __restrict__ ln1_b,
    __hip_bfloat16* hbuf1)
{
    __shared__ short tile[64][65];
    __shared__ float sm1[4], sm2[4];
    __shared__ float smu, srs;
    int id = blockIdx.x;
    int t = threadIdx.x;
    if (id >= 3072) {
        // ---- LN1 row ----
        int row = id - 3072;
        const float* xr = x + (size_t)row * C_;
        float v[4]; float s = 0.f, ss = 0.f;
#pragma unroll
        for (int i = 0; i < 4; i++) {
            float f = xr[t + i * 256];
            v[i] = f; s += f; ss += f * f;
        }
#pragma unroll
        for (int off = 32; off >= 1; off >>= 1) {
            s  += __shfl_xor(s,  off);
            ss += __shfl_xor(ss, off);
        }
        int wave = t >> 6, lane = t & 63;
        if (!lane) { sm1[wave] = s; sm2[wave] = ss; }
        __syncthreads();
        if (t == 0) {
            s  = sm1[0] + sm1[1] + sm1[2] + sm1[3];
            ss = sm2[0] + sm2[1] + sm2[2] + sm2[3];
            float mu  = s * (1.f / C_);
            float var = ss * (1.f / C_) - mu * mu;
            if (var < 0.f) var = 0.f;
            smu = mu; srs = rsqrtf(var + 1e-5f);
        }
        __syncthreads();
        float mu = smu, rs = srs;
#pragma unroll
        for (int i = 0; i < 4; i++) {
            int c = t + i * 256;
            hbuf1[(size_t)row * C_ + c] = __float2bfloat16((v[i] - mu) * rs * ln1_g[c] + ln1_b[c]);
        }
        return;
    }
    // ---- weight convert+transpose ----
    const float* W; short* Wt; int K, N;
    if (id < 768)       { W = qkv_w; Wt = qkvwT; K = C_; N = 3 * C_; }
    else if (id < 1024) { id -= 768;  W = out_w; Wt = outwT; K = C_; N = C_; }
    else if (id < 2048) { id -= 1024; W = ff1_w; Wt = ff1wT; K = C_; N = F_; }
    else                { id -= 2048; W = ff2_w; Wt = ff2wT; K = F_; N = C_; }
    int ntile = N >> 6;
    int n0 = (id % ntile) * 64, k0 = (id / ntile) * 64;
#pragma unroll
    for (int i = 0; i < 4; i++) {
        int idx = t + i * 256;
        int r = idx >> 4, c4 = (idx & 15) * 4;
        float4 u = *(const float4*)(W + (size_t)(k0 + r) * N + n0 + c4);
        tile[c4 + 0][r] = f2bfraw(u.x);
        tile[c4 + 1][r] = f2bfraw(u.y);
        tile[c4 + 2][r] = f2bfraw(u.z);
        tile[c4 + 3][r] = f2bfraw(u.w);
    }
    __syncthreads();
#pragma unroll
    for (int i = 0; i < 2; i++) {
        int idx = t + i * 256;
        int r = idx >> 3, c8 = (idx & 7) * 8;
        short v[8];
#pragma unroll
        for (int u8 = 0; u8 < 8; u8++) v[u8] = tile[r][c8 + u8];
        *(uint4*)(Wt + (size_t)(n0 + r) * K + k0 + c8) = *(const uint4*)v;
    }
}

// ---------------- fused LayerNorm (fp32 in, bf16 out) ----------------
__global__ __launch_bounds__(256) void ln_fused(const float* __restrict__ x, int ldx,
                                                const float* __restrict__ g,
                                                const float* __restrict__ b,
                                                __hip_bfloat16* out, int ldo)
{
    __shared__ float sm1[4], sm2[4];
    __shared__ float smu, srs;
    int row = blockIdx.x, t = threadIdx.x;
    const float* xr = x + (size_t)row * ldx;
    float v[4]; float s = 0.f, ss = 0.f;
#pragma unroll
    for (int i = 0; i < 4; i++) {
        float f = xr[t + i * 256];
        v[i] = f; s += f; ss += f * f;
    }
#pragma unroll
    for (int off = 32; off >= 1; off >>= 1) {
        s  += __shfl_xor(s,  off);
        ss += __shfl_xor(ss, off);
    }
    int wave = t >> 6, lane = t & 63;
    if (!lane) { sm1[wave] = s; sm2[wave] = ss; }
    __syncthreads();
    if (t == 0) {
        s  = sm1[0] + sm1[1] + sm1[2] + sm1[3];
        ss = sm2[0] + sm2[1] + sm2[2] + sm2[3];
        float mu  = s * (1.f / C_);
        float var = ss * (1.f / C_) - mu * mu;
        if (var < 0.f) var = 0.f;
        smu = mu; srs = rsqrtf(var + 1e-5f);
    }
    __syncthreads();
    float mu = smu, rs = srs;
#pragma unroll
    for (int i = 0; i < 4; i++) {
        int c = t + i * 256;
        out[(size_t)row * ldo + c] = __float2bfloat16((v[i] - mu) * rs * g[c] + b[c]);
    }
}

// ---------------- 128x128 MFMA GEMM, 3-deep counted-vmcnt pipeline ----------
// out = A[M,K](bf16) @ Wt[N,K]^T + bias. Out bf16.
// ACT: 0 = plain; 1 = GELU; 3 = QKV-mode: cols < 2048 (Q,K) written normally,
// cols >= 2048 (V) written ONLY transposed into out2[b*H+h][d][t]
// (n-blocks are 128-wide so the branch is block-uniform).
// koff applies to Wt ONLY; A reads k from 0.
template<int ACT>
__global__ __launch_bounds__(256) void gemm128(
    const __hip_bfloat16* A, int lda,
    const short* Wt, int ldw, int noff, int koff,
    const float* __restrict__ bias, int boff,
    void* out, int ldo,
    short* out2,
    int K)
{
    __shared__ __align__(16) short As[3][128 * 32];
    __shared__ __align__(16) short Bs[3][128 * 32];
    int tid = threadIdx.x;
    int w = tid >> 6, lane = tid & 63;
    int quad = lane >> 4, l16 = lane & 15;
    int wm = w >> 1, wn = w & 1;
    int m0 = blockIdx.y * 128, n0 = blockIdx.x * 128;
    int lr = lane >> 2, lk = (lane & 3) * 8;

    const __hip_bfloat16* Ag = A + (size_t)(m0 + w * 32 + lr) * lda + lk;
    const short*          Bg = Wt + (size_t)(noff + n0 + w * 32 + lr) * ldw + koff + lk;

    f32x4 acc[4][4];
#pragma unroll
    for (int i = 0; i < 4; i++)
#pragma unroll
        for (int j = 0; j < 4; j++) acc[i][j] = (f32x4){0.f, 0.f, 0.f, 0.f};

    const int NT = K >> 5;
    // prologue: stage tile 0 -> buf0, tile 1 -> buf1
    {
        gl2lds16(Ag,            &As[0][(w * 32) * 32]);
        gl2lds16(Ag + 16 * lda, &As[0][(w * 32 + 16) * 32]);
        gl2lds16(Bg,            &Bs[0][(w * 32) * 32]);
        gl2lds16(Bg + 16 * ldw, &Bs[0][(w * 32 + 16) * 32]);
        if (NT > 1) {
            gl2lds16(Ag + 32,            &As[1][(w * 32) * 32]);
            gl2lds16(Ag + 16 * lda + 32, &As[1][(w * 32 + 16) * 32]);
            gl2lds16(Bg + 32,            &Bs[1][(w * 32) * 32]);
            gl2lds16(Bg + 16 * ldw + 32, &Bs[1][(w * 32 + 16) * 32]);
        }
    }

    int cur = 0;   // buffer holding tile t (cur == t % 3)
    for (int t = 0; t < NT; t++) {
        if (t + 2 < NT) {
            int sb = cur + 2; if (sb >= 3) sb -= 3;
            int ko = (t + 2) << 5;
            gl2lds16(Ag + ko,            &As[sb][(w * 32) * 32]);
            gl2lds16(Ag + 16 * lda + ko, &As[sb][(w * 32 + 16) * 32]);
            gl2lds16(Bg + ko,            &Bs[sb][(w * 32) * 32]);
            gl2lds16(Bg + 16 * ldw + ko, &Bs[sb][(w * 32 + 16) * 32]);
        }
        int ahead = NT - 1 - t;
        if (ahead >= 2)      asm volatile("s_waitcnt vmcnt(8)" ::: "memory");
        else if (ahead == 1) asm volatile("s_waitcnt vmcnt(4)" ::: "memory");
        else                 asm volatile("s_waitcnt vmcnt(0)" ::: "memory");
        __builtin_amdgcn_s_barrier();
        __builtin_amdgcn_sched_barrier(0);

        bf16x8 af[4], bfr[4];
#pragma unroll
        for (int mt = 0; mt < 4; mt++)
            af[mt] = *(const bf16x8*)&As[cur][(wm * 64 + mt * 16 + l16) * 32 + quad * 8];
#pragma unroll
        for (int nt = 0; nt < 4; nt++)
            bfr[nt] = *(const bf16x8*)&Bs[cur][(wn * 64 + nt * 16 + l16) * 32 + quad * 8];
#pragma unroll
        for (int mt = 0; mt < 4; mt++)
#pragma unroll
            for (int nt = 0; nt < 4; nt++)
                acc[mt][nt] = __builtin_amdgcn_mfma_f32_16x16x32_bf16(af[mt], bfr[nt], acc[mt][nt], 0, 0, 0);

        __builtin_amdgcn_sched_barrier(0);
        __builtin_amdgcn_s_barrier();   // reads of buf cur retired before overwrite
        cur = (cur == 2) ? 0 : cur + 1;
    }

#pragma unroll
    for (int nt = 0; nt < 4; nt++) {
        int c = n0 + wn * 64 + nt * 16 + l16;
        float bv = bias ? bias[boff + c] : 0.f;
        if (ACT == 3 && c >= 2048) {
            // V output: write transposed into out2[b*H+h][d][t]
            int hh = (c - 2048) >> 6, d = (c - 2048) & 63;
#pragma unroll
            for (int mt = 0; mt < 4; mt++) {
                int r0 = m0 + wm * 64 + mt * 16 + quad * 4;
                short vals[4];
#pragma unroll
                for (int reg = 0; reg < 4; reg++)
                    vals[reg] = f2bfraw(acc[mt][nt][reg] + bv);
                int bb = r0 >> 11, tt = r0 & 2047;
                *(uint2*)(out2 + ((size_t)(bb * H_ + hh) * D_ + d) * T_ + tt)
                    = *(const uint2*)vals;
            }
        } else {
#pragma unroll
            for (int mt = 0; mt < 4; mt++) {
#pragma unroll
                for (int reg = 0; reg < 4; reg++) {
                    int r = m0 + wm * 64 + mt * 16 + quad * 4 + reg;
                    float v = acc[mt][nt][reg] + bv;
                    if (ACT == 1) v = 0.5f * v * (1.f + erff(v * 0.70710678118654752f));
                    ((__hip_bfloat16*)out)[(size_t)r * ldo + c] = __float2bfloat16(v);
                }
            }
        }
    }
}

// ------- 128Mx64N MFMA GEMM, fp32 out + residual, 3-deep counted-vmcnt ------
// Wave-tile 64Mx32N: 6 ds_read : 8 MFMA per k-step. 36 KB LDS.
// out[r][c] = A@Wt^T + (bias?) + res[r][c] (res may alias out: in-place RMW).
// koff applies to Wt ONLY; A reads k from 0.
__global__ __launch_bounds__(256) void gemm64n(
    const __hip_bfloat16* A, int lda,
    const short* Wt, int ldw, int koff,
    const float* __restrict__ bias,
    const float* res, int ldres,
    float* out, int ldo,
    int K)
{
    __shared__ __align__(16) short As[3][128 * 32];   // [m][k]
    __shared__ __align__(16) short Bs[3][64 * 32];    // [n][k]
    int tid = threadIdx.x;
    int w = tid >> 6, lane = tid & 63;
    int quad = lane >> 4, l16 = lane & 15;
    int wm = w >> 1, wn = w & 1;                   // 2x2 wave grid
    int m0 = blockIdx.y * 128, n0 = blockIdx.x * 64;
    int lr = lane >> 2, lk = (lane & 3) * 8;

    const __hip_bfloat16* Ag = A + (size_t)(m0 + w * 32 + lr) * lda + lk;          // no koff
    const short*          Bg = Wt + (size_t)(n0 + w * 16 + lr) * ldw + koff + lk;  // koff here only

    f32x4 acc[4][2];
#pragma unroll
    for (int i = 0; i < 4; i++)
#pragma unroll
        for (int j = 0; j < 2; j++) acc[i][j] = (f32x4){0.f, 0.f, 0.f, 0.f};

    const int NT = K >> 5;
    // prologue: stage tile 0 -> buf0, tile 1 -> buf1
    {
        gl2lds16(Ag,            &As[0][(w * 32) * 32]);
        gl2lds16(Ag + 16 * lda, &As[0][(w * 32 + 16) * 32]);
        gl2lds16(Bg,            &Bs[0][(w * 16) * 32]);
        if (NT > 1) {
            gl2lds16(Ag + 32,            &As[1][(w * 32) * 32]);
            gl2lds16(Ag + 16 * lda + 32, &As[1][(w * 32 + 16) * 32]);
            gl2lds16(Bg + 32,            &Bs[1][(w * 16) * 32]);
        }
    }

    int cur = 0;
    for (int t = 0; t < NT; t++) {
        if (t + 2 < NT) {
            int sb = cur + 2; if (sb >= 3) sb -= 3;
            int ko = (t + 2) << 5;
            gl2lds16(Ag + ko,            &As[sb][(w * 32) * 32]);
            gl2lds16(Ag + 16 * lda + ko, &As[sb][(w * 32 + 16) * 32]);
            gl2lds16(Bg + ko,            &Bs[sb][(w * 16) * 32]);
        }
        int ahead = NT - 1 - t;
        if (ahead >= 2)      asm volatile("s_waitcnt vmcnt(6)" ::: "memory");
        else if (ahead == 1) asm volatile("s_waitcnt vmcnt(3)" ::: "memory");
        else                 asm volatile("s_waitcnt vmcnt(0)" ::: "memory");
        __builtin_amdgcn_s_barrier();
        __builtin_amdgcn_sched_barrier(0);

        bf16x8 af[4], bfr[2];
#pragma unroll
        for (int mt = 0; mt < 4; mt++)
            af[mt] = *(const bf16x8*)&As[cur][(wm * 64 + mt * 16 + l16) * 32 + quad * 8];
#pragma unroll
        for (int nt = 0; nt < 2; nt++)
            bfr[nt] = *(const bf16x8*)&Bs[cur][(wn * 32 + nt * 16 + l16) * 32 + quad * 8];
#pragma unroll
        for (int mt = 0; mt < 4; mt++)
#pragma unroll
            for (int nt = 0; nt < 2; nt++)
                acc[mt][nt] = __builtin_amdgcn_mfma_f32_16x16x32_bf16(af[mt], bfr[nt], acc[mt][nt], 0, 0, 0);

        __builtin_amdgcn_sched_barrier(0);
        __builtin_amdgcn_s_barrier();
        cur = (cur == 2) ? 0 : cur + 1;
    }

#pragma unroll
    for (int nt = 0; nt < 2; nt++) {
        int c = n0 + wn * 32 + nt * 16 + l16;
        float bv = bias ? bias[c] : 0.f;
#pragma unroll
        for (int mt = 0; mt < 4; mt++) {
#pragma unroll
            for (int reg = 0; reg < 4; reg++) {
                int r = m0 + wm * 64 + mt * 16 + quad * 4 + reg;
                float v = acc[mt][nt][reg] + bv + res[(size_t)r * ldres + c];
                out[(size_t)r * ldo + c] = v;
            }
        }
    }
}

// ---------------- MFMA flash attention: R5-exact math, 128-key stages -------
__global__ __launch_bounds__(256, 2) void attn_flash(__hip_bfloat16* qkv,
                                                     const short* __restrict__ vt)
{
    __shared__ __align__(16) short Ks[2][2][64 * 64];   // [buf][sub][kvrow][d]
    __shared__ __align__(16) short Vs[2][2][64 * 64];   // [buf][sub][d][kvcol]
    __shared__ __align__(16) short Pl[4][16 * 72];      // wave-private P
    int tid = threadIdx.x;
    int wave = tid >> 6, lane = tid & 63;
    int quad = lane >> 4, l16 = lane & 15;
    int fid = blockIdx.x + 16 * blockIdx.y;          // 0..255
    int h = (fid & 7) * 2 + ((fid >> 3) >> 4);
    int i = (fid >> 3) & 15;
    int b = blockIdx.z;
    int qbs[2]; qbs[0] = i; qbs[1] = 31 - i;
    const size_t rs = 3 * C_;
    __hip_bfloat16* base = qkv + (size_t)b * T_ * rs;
    const __hip_bfloat16* Qb = base + h * D_;
    const __hip_bfloat16* Kb = base + C_ + h * D_;
    const short* Vt = vt + (size_t)(b * H_ + h) * D_ * T_;

    bf16x8 qf[2][2];
#pragma unroll
    for (int tq = 0; tq < 2; tq++) {
        const __hip_bfloat16* qr = Qb + (size_t)(qbs[tq] * 64 + wave * 16 + l16) * rs + quad * 8;
        qf[tq][0] = *(const bf16x8*)qr;
        qf[tq][1] = *(const bf16x8*)(qr + 32);
    }

    f32x4 o[2][4];
    float m[2][4], l[2][4];
#pragma unroll
    for (int tq = 0; tq < 2; tq++)
#pragma unroll
        for (int t = 0; t < 4; t++) {
            o[tq][t] = (f32x4){0.f, 0.f, 0.f, 0.f};
            m[tq][t] = -INFINITY;
            l[tq][t] = 0.f;
        }
    short* Pw = &Pl[wave][0];

    int srow = wave * 16 + (lane >> 3);
    int scg  = ((lane & 7) ^ (lane >> 3)) * 8;
    const __hip_bfloat16* Kg = Kb + (size_t)srow * rs + scg;
    const short*          Vg = Vt + (size_t)srow * T_ + scg;

    int qhi = qbs[1];
    int NS = (qhi >> 1) + 1;
    int swz = (l16 & 7);
    int cur = 0;

#pragma unroll
    for (int sub = 0; sub < 2; sub++)
#pragma unroll
        for (int j = 0; j < 2; j++) {
            gl2lds16(Kg + (size_t)(sub * 64 + j * 8) * rs, &Ks[0][sub][(wave * 2 + j) * 512]);
            gl2lds16(Vg + (size_t)(j * 8) * T_ + sub * 64, &Vs[0][sub][(wave * 2 + j) * 512]);
        }
    __syncthreads();

    for (int s = 0; s < NS; s++) {
        if (s + 1 < NS) {
            int kb = (s + 1) * 128;
#pragma unroll
            for (int sub = 0; sub < 2; sub++)
#pragma unroll
                for (int j = 0; j < 2; j++) {
                    gl2lds16(Kg + (size_t)(kb + sub * 64 + j * 8) * rs, &Ks[cur ^ 1][sub][(wave * 2 + j) * 512]);
                    gl2lds16(Vg + (size_t)(j * 8) * T_ + kb + sub * 64, &Vs[cur ^ 1][sub][(wave * 2 + j) * 512]);
                }
        }
#pragma unroll
        for (int sub = 0; sub < 2; sub++) {
            int kt = 2 * s + sub;
            if (kt > qhi) break;
            const short* Kc = Ks[cur][sub];
            const short* Vc = Vs[cur][sub];
#pragma unroll
            for (int tq = 0; tq < 2; tq++) {
                if (kt > qbs[tq]) continue;
                f32x4 sa[4];
                __builtin_amdgcn_s_setprio(1);
#pragma unroll
                for (int t16 = 0; t16 < 4; t16++) {
                    int row = t16 * 16 + l16;
                    bf16x8 kf0 = *(const bf16x8*)&Kc[row * 64 + ((quad     ^ swz)) * 8];
                    bf16x8 kf1 = *(const bf16x8*)&Kc[row * 64 + (((quad + 4) ^ swz)) * 8];
                    f32x4 sv = (f32x4){0.f, 0.f, 0.f, 0.f};
                    sv = __builtin_amdgcn_mfma_f32_16x16x32_bf16(qf[tq][0], kf0, sv, 0, 0, 0);
                    sv = __builtin_amdgcn_mfma_f32_16x16x32_bf16(qf[tq][1], kf1, sv, 0, 0, 0);
                    sa[t16] = sv;
                }
                __builtin_amdgcn_s_setprio(0);
                bool maskit = (kt == qbs[tq]);
#pragma unroll
                for (int t16 = 0; t16 < 4; t16++) {
#pragma unroll
                    for (int reg = 0; reg < 4; reg++) {
                        float v = sa[t16][reg] * 0.125f;
                        if (maskit) {
                            int keyl = t16 * 16 + l16;
                            int ql = wave * 16 + quad * 4 + reg;
                            if (keyl > ql) v = -3.0e38f;
                        }
                        sa[t16][reg] = v;
                    }
                }
                float mx[4];
#pragma unroll
                for (int reg = 0; reg < 4; reg++)
                    mx[reg] = fmaxf(fmaxf(sa[0][reg], sa[1][reg]), fmaxf(sa[2][reg], sa[3][reg]));
#pragma unroll
                for (int off = 8; off >= 1; off >>= 1)
#pragma unroll
                    for (int reg = 0; reg < 4; reg++)
                        mx[reg] = fmaxf(mx[reg], __shfl_xor(mx[reg], off));
                float alpha[4];
#pragma unroll
                for (int reg = 0; reg < 4; reg++) {
                    float mn = fmaxf(m[tq][reg], mx[reg]);
                    alpha[reg] = __expf(m[tq][reg] - mn);
                    m[tq][reg] = mn;
                }
                float rsum[4] = {0.f, 0.f, 0.f, 0.f};
#pragma unroll
                for (int t16 = 0; t16 < 4; t16++) {
#pragma unroll
                    for (int reg = 0; reg < 4; reg++) {
                        float p = __expf(sa[t16][reg] - m[tq][reg]);
                        rsum[reg] += p;
                        Pw[(quad * 4 + reg) * 72 + t16 * 16 + l16] = f2bfraw(p);
                    }
                }
#pragma unroll
                for (int off = 8; off >= 1; off >>= 1)
#pragma unroll
                    for (int reg = 0; reg < 4; reg++)
                        rsum[reg] += __shfl_xor(rsum[reg], off);
#pragma unroll
                for (int reg = 0; reg < 4; reg++)
                    l[tq][reg] = l[tq][reg] * alpha[reg] + rsum[reg];
#pragma unroll
                for (int t = 0; t < 4; t++)
#pragma unroll
                    for (int reg = 0; reg < 4; reg++)
                        o[tq][t][reg] *= alpha[reg];
                __builtin_amdgcn_s_setprio(1);
#pragma unroll
                for (int chunk = 0; chunk < 2; chunk++) {
                    bf16x8 pf = *(const bf16x8*)&Pw[l16 * 72 + chunk * 32 + quad * 8];
#pragma unroll
                    for (int dt = 0; dt < 4; dt++) {
                        int row = dt * 16 + l16;
                        bf16x8 vf = *(const bf16x8*)&Vc[row * 64 + (((chunk * 4 + quad) ^ swz)) * 8];
                        o[tq][dt] = __builtin_amdgcn_mfma_f32_16x16x32_bf16(pf, vf, o[tq][dt], 0, 0, 0);
                    }
                }
                __builtin_amdgcn_s_setprio(0);
            }
        }
        __syncthreads();
        cur ^= 1;
    }

#pragma unroll
    for (int tq = 0; tq < 2; tq++) {
#pragma unroll
        for (int dt = 0; dt < 4; dt++) {
#pragma unroll
            for (int reg = 0; reg < 4; reg++) {
                int r = qbs[tq] * 64 + wave * 16 + quad * 4 + reg;
                float v = o[tq][dt][reg] / l[tq][reg];
                base[(size_t)r * rs + h * D_ + dt * 16 + l16] = __float2bfloat16(v);
            }
        }
    }
}

extern "C" void kernel_launch(void* const* d_in, const int* in_sizes, int n_in,
                              void* d_out, int out_size, void* d_ws, size_t ws_size,
                              hipStream_t stream)
{
    const float* x     = (const float*)d_in[0];
    const float* ln1_g = (const float*)d_in[1];
    const float* ln1_b = (const float*)d_in[2];
    const float* qkv_w = (const float*)d_in[3];
    const float* qkv_b = (const float*)d_in[4];
    const float* out_w = (const float*)d_in[5];
    const float* out_b = (const float*)d_in[6];
    const float* ln2_g = (const float*)d_in[7];
    const float* ln2_b = (const float*)d_in[8];
    const float* ff1_w = (const float*)d_in[9];
    const float* ff1_b = (const float*)d_in[10];
    const float* ff2_w = (const float*)d_in[11];
    const float* ff2_b = (const float*)d_in[12];

    // ws (48 MiB): [0,24M) qkv bf16 [4096][3072]
    //   Q cols 0..1023: q -> attn-out -> hbuf2 (LN2 out, live whole FF phase)
    //   K cols 1024..2047; V cols 2048..3071 unused (V goes straight to vtbuf);
    //   K+V slots reused as ff1 act chunk (width 2048, per chunk) later.
    //   [24M,30M) qkvW^T; [30M,32M) outW^T; [32M,40M) ff1W^T; [40M,48M) ff2W^T
    // d_out (16 MiB fp32 [4096][1024]):
    //   phase 1: [0,8M) hbuf1 bf16 (LN1 out, A of QKV GEMM);
    //            [8M,16M) vtbuf bf16 [B*H][64 d][2048 t] (QKV epilogue; dead
    //            after attention)
    //   phase 2: x1 residual fp32 (out-proj), FF2 accumulates in place.
    char* ws = (char*)d_ws;
    __hip_bfloat16* qkv = (__hip_bfloat16*)ws;
    short* qkvwT = (short*)(ws + 25165824);
    short* outwT = (short*)(ws + 31457280);
    short* ff1wT = (short*)(ws + 33554432);
    short* ff2wT = (short*)(ws + 41943040);
    __hip_bfloat16* hbuf2 = qkv;                           // Q slots, ld 3072
    __hip_bfloat16* act   = qkv + 1024;                    // K+V slots, ld 3072
    __hip_bfloat16* hbuf1 = (__hip_bfloat16*)d_out;        // ld 1024 (bf16)
    float* x1 = (float*)d_out;                             // fp32, ld 1024
    short* vtbuf = (short*)d_out + 4194304;                // bf16 Vt at [8M,16M)

    // 0) weight convert+transpose + LN1, single launch (independent work)
    wconv_ln1<<<7168, 256, 0, stream>>>(qkv_w, qkvwT, out_w, outwT,
                                        ff1_w, ff1wT, ff2_w, ff2wT,
                                        x, ln1_g, ln1_b, hbuf1);

    // 1) QKV: hbuf1 @ qkv_w + qkv_b -> Q,K into qkv; V transposed into vtbuf
    gemm128<3><<<dim3(3 * C_ / 128, BT_ / 128), 256, 0, stream>>>(
        hbuf1, C_, qkvwT, C_, 0, 0, qkv_b, 0, qkv, 3 * C_, vtbuf, C_);
    // 2) attention -> Q slots (paired q-tiles, 128-key pipelined LDS stages)
    attn_flash<<<dim3(16, H_, B_), 256, 0, stream>>>(qkv, vtbuf);
    // 3) out proj + residual(x) -> x1 = d_out (fp32); Q slots + Vt dead after
    gemm64n<<<dim3(C_ / 64, BT_ / 128), 256, 0, stream>>>(
        qkv, 3 * C_, outwT, C_, 0, out_b, x, C_, x1, C_, C_);
    // 4) LN2(x1) -> hbuf2 (Q slots)
    ln_fused<<<BT_, 256, 0, stream>>>(x1, C_, ln2_g, ln2_b, hbuf2, 3 * C_);
    // 5) FF in two 2048-wide chunks; act in K+V slots; FF2 accumulates into
    //    d_out in place.
    for (int f = 0; f < 2; f++) {
        gemm128<1><<<dim3(2048 / 128, BT_ / 128), 256, 0, stream>>>(
            hbuf2, 3 * C_, ff1wT, C_, f * 2048, 0, ff1_b, f * 2048,
            act, 3 * C_, nullptr, C_);
        gemm64n<<<dim3(C_ / 64, BT_ / 128), 256, 0, stream>>>(
            act, 3 * C_, ff2wT, F_, f * 2048, (f == 0 ? ff2_b : nullptr),
            x1, C_, x1, C_, 2048);
    }
}